// Round 1
// baseline (751.688 us; speedup 1.0000x reference)
//
#include <hip/hip_runtime.h>
#include <hip/hip_bf16.h>

typedef __bf16 bf16;
typedef __attribute__((ext_vector_type(8))) __bf16 bf16x8;
typedef __attribute__((ext_vector_type(4))) float f32x4;

#define D_MODEL 1024
#define NHEADS  16
#define DK      64
#define DFF     4096
#define BATCH   4
#define SEQ     2048
#define NTOK    (BATCH*SEQ)   // 8192

// ---------------------------------------------------------------- transpose+cast
// W[K][N] fp32 -> Wt[N][K] bf16   (so GEMM B-fragments read contiguous k)
__global__ __launch_bounds__(256) void transpose_cast(
    const float* __restrict__ W, bf16* __restrict__ Wt, int K, int N)
{
    __shared__ float tile[32][33];
    const int tx = threadIdx.x, ty = threadIdx.y;
    const int n0 = blockIdx.x * 32, k0 = blockIdx.y * 32;
#pragma unroll
    for (int i = 0; i < 4; ++i)
        tile[ty + i*8][tx] = W[(size_t)(k0 + ty + i*8) * N + n0 + tx];
    __syncthreads();
#pragma unroll
    for (int i = 0; i < 4; ++i)
        Wt[(size_t)(n0 + ty + i*8) * K + k0 + tx] = (bf16)tile[tx][ty + i*8];
}

// ---------------------------------------------------------------- layernorm (fp32 in, bf16 out)
__global__ __launch_bounds__(256) void ln_kernel(
    const float* __restrict__ x, const float* __restrict__ g,
    const float* __restrict__ beta, bf16* __restrict__ out)
{
    const int row = blockIdx.x, tid = threadIdx.x;
    const f32x4* xr = (const f32x4*)(x + (size_t)row * D_MODEL);
    f32x4 v = xr[tid];
    float s  = v[0] + v[1] + v[2] + v[3];
    float s2 = v[0]*v[0] + v[1]*v[1] + v[2]*v[2] + v[3]*v[3];
#pragma unroll
    for (int off = 32; off > 0; off >>= 1) {
        s  += __shfl_down(s,  off, 64);
        s2 += __shfl_down(s2, off, 64);
    }
    __shared__ float red[8];
    const int wave = tid >> 6, lane = tid & 63;
    if (lane == 0) { red[wave] = s; red[wave + 4] = s2; }
    __syncthreads();
    if (tid == 0) {
        float a = red[0] + red[1] + red[2] + red[3];
        float c = red[4] + red[5] + red[6] + red[7];
        float mu  = a * (1.0f / D_MODEL);
        float var = c * (1.0f / D_MODEL) - mu * mu;
        red[0] = mu;
        red[1] = rsqrtf(var + 1e-5f);
    }
    __syncthreads();
    const float mu = red[0], rs = red[1];
    f32x4 gv = ((const f32x4*)g)[tid];
    f32x4 bv = ((const f32x4*)beta)[tid];
    union { bf16 h[4]; uint2 u; } o;
#pragma unroll
    for (int i = 0; i < 4; ++i) o.h[i] = (bf16)((v[i] - mu) * rs * gv[i] + bv[i]);
    *(uint2*)(out + (size_t)row * D_MODEL + tid * 4) = o.u;
}

// ---------------------------------------------------------------- bf16 GEMM, 128x128 tile, BK=32
// A[M][K] bf16 row-major, Bt[N][K] bf16 row-major (= B^T), C = A·B + bias (+epilogue)
// EPI 0: head-scatter bf16 out[bh][s][dk]   (QKV)
// EPI 1: fp32 out = acc + bias + resid      (O-proj, FFN2)
// EPI 2: bf16 out = relu(acc + bias)        (FFN1)
template<int EPI>
__global__ __launch_bounds__(256, 2) void gemm_bf16(
    const bf16* __restrict__ A, const bf16* __restrict__ Bt,
    const float* __restrict__ bias, const float* __restrict__ resid,
    void* __restrict__ outp, int M, int N, int K)
{
    __shared__ __align__(16) bf16 As[128 * 40];
    __shared__ __align__(16) bf16 Bs[128 * 40];
    const int tid  = threadIdx.x;
    const int wave = tid >> 6, lane = tid & 63;
    const int quad = lane >> 4, l16 = lane & 15;
    const int wr = wave >> 1, wc = wave & 1;
    const int m0 = blockIdx.y * 128, n0 = blockIdx.x * 128;

    const f32x4 vzero = {0.f, 0.f, 0.f, 0.f};
    f32x4 acc[4][4];
#pragma unroll
    for (int i = 0; i < 4; ++i)
#pragma unroll
        for (int j = 0; j < 4; ++j) acc[i][j] = vzero;

    const int sr = tid >> 2;         // staging row 0..63
    const int sc = (tid & 3) * 8;    // staging col 0,8,16,24

    for (int k0 = 0; k0 < K; k0 += 32) {
        __syncthreads();
        *(f32x4*)&As[sr * 40 + sc]        = *(const f32x4*)&A [(size_t)(m0 + sr)      * K + k0 + sc];
        *(f32x4*)&As[(sr + 64) * 40 + sc] = *(const f32x4*)&A [(size_t)(m0 + sr + 64) * K + k0 + sc];
        *(f32x4*)&Bs[sr * 40 + sc]        = *(const f32x4*)&Bt[(size_t)(n0 + sr)      * K + k0 + sc];
        *(f32x4*)&Bs[(sr + 64) * 40 + sc] = *(const f32x4*)&Bt[(size_t)(n0 + sr + 64) * K + k0 + sc];
        __syncthreads();
        bf16x8 af[4], bfr[4];
#pragma unroll
        for (int i = 0; i < 4; ++i) af[i]  = *(const bf16x8*)&As[(wr * 64 + i * 16 + l16) * 40 + quad * 8];
#pragma unroll
        for (int j = 0; j < 4; ++j) bfr[j] = *(const bf16x8*)&Bs[(wc * 64 + j * 16 + l16) * 40 + quad * 8];
#pragma unroll
        for (int i = 0; i < 4; ++i)
#pragma unroll
            for (int j = 0; j < 4; ++j)
                acc[i][j] = __builtin_amdgcn_mfma_f32_16x16x32_bf16(af[i], bfr[j], acc[i][j], 0, 0, 0);
    }

#pragma unroll
    for (int i = 0; i < 4; ++i) {
#pragma unroll
        for (int j = 0; j < 4; ++j) {
            const int col = n0 + wc * 64 + j * 16 + l16;
            const float bcol = bias[col];
#pragma unroll
            for (int r = 0; r < 4; ++r) {
                const int row = m0 + wr * 64 + i * 16 + quad * 4 + r;
                const float v = acc[i][j][r] + bcol;
                if (EPI == 0) {
                    const int bb = row >> 11, ss = row & (SEQ - 1);
                    const int hh = col >> 6,  dd = col & (DK - 1);
                    ((bf16*)outp)[((size_t)(bb * NHEADS + hh) * SEQ + ss) * DK + dd] = (bf16)v;
                } else if (EPI == 1) {
                    const size_t idx = (size_t)row * N + col;
                    ((float*)outp)[idx] = v + resid[idx];
                } else {
                    ((bf16*)outp)[(size_t)row * N + col] = (bf16)fmaxf(v, 0.f);
                }
            }
        }
    }
}

// ---------------------------------------------------------------- flash attention (causal)
// Q/K/V: [B*H][S][DK] bf16.  out: [B][S][H*DK] bf16 token-major.
// Block = 256 thr (4 waves); block owns 128 q rows; wave owns 32 q rows.
__global__ __launch_bounds__(256, 2) void attn_kernel(
    const bf16* __restrict__ Q, const bf16* __restrict__ K,
    const bf16* __restrict__ V, bf16* __restrict__ out)
{
    const int bh = blockIdx.y, qt = blockIdx.x;
    const int tid  = threadIdx.x;
    const int wave = tid >> 6, lane = tid & 63;
    const int quad = lane >> 4, l16 = lane & 15;
    const int q0 = qt * 128;
    const int b = bh >> 4, h = bh & 15;

    __shared__ __align__(16) bf16 Ks[64 * 72];
    __shared__ __align__(16) bf16 Vt[64 * 72];      // V transposed: Vt[d][kv]
    __shared__ __align__(16) bf16 Ps[4][32 * 72];   // per-wave P round-trip

    const bf16* Qb = Q + (size_t)bh * SEQ * DK;
    const bf16* Kb = K + (size_t)bh * SEQ * DK;
    const bf16* Vb = V + (size_t)bh * SEQ * DK;

    // Q fragments held in registers for the whole block
    bf16x8 qf[2][2];
#pragma unroll
    for (int qi = 0; qi < 2; ++qi)
#pragma unroll
        for (int kk = 0; kk < 2; ++kk) {
            const int q = q0 + wave * 32 + qi * 16 + l16;
            qf[qi][kk] = *(const bf16x8*)&Qb[(size_t)q * DK + kk * 32 + quad * 8];
        }

    const f32x4 vzero = {0.f, 0.f, 0.f, 0.f};
    f32x4 Oacc[2][4];
    float mrow[2][4], lrow[2][4];
#pragma unroll
    for (int qi = 0; qi < 2; ++qi) {
#pragma unroll
        for (int dj = 0; dj < 4; ++dj) Oacc[qi][dj] = vzero;
#pragma unroll
        for (int r = 0; r < 4; ++r) { mrow[qi][r] = -3.0e38f; lrow[qi][r] = 0.f; }
    }

    const int nkt = 2 * qt + 2;   // causal: only kv <= block's max q
    for (int kt = 0; kt < nkt; ++kt) {
        const int kv0 = kt * 64;
        __syncthreads();
        // stage K tile [64][64] and V^T tile
        for (int c = tid; c < 512; c += 256) {
            const int r = c >> 3, d0 = (c & 7) * 8;
            *(f32x4*)&Ks[r * 72 + d0] = *(const f32x4*)&Kb[(size_t)(kv0 + r) * DK + d0];
            bf16x8 vv = *(const bf16x8*)&Vb[(size_t)(kv0 + r) * DK + d0];
#pragma unroll
            for (int i = 0; i < 8; ++i) Vt[(d0 + i) * 72 + r] = vv[i];
        }
        __syncthreads();

        // S = Q K^T  (32 q x 64 kv per wave)
        bf16x8 kf[4][2];
#pragma unroll
        for (int j = 0; j < 4; ++j)
#pragma unroll
            for (int kk = 0; kk < 2; ++kk)
                kf[j][kk] = *(const bf16x8*)&Ks[(j * 16 + l16) * 72 + kk * 32 + quad * 8];

        f32x4 sv[2][4];
#pragma unroll
        for (int qi = 0; qi < 2; ++qi)
#pragma unroll
            for (int j = 0; j < 4; ++j) {
                f32x4 t = vzero;
                t = __builtin_amdgcn_mfma_f32_16x16x32_bf16(qf[qi][0], kf[j][0], t, 0, 0, 0);
                t = __builtin_amdgcn_mfma_f32_16x16x32_bf16(qf[qi][1], kf[j][1], t, 0, 0, 0);
                sv[qi][j] = t;
            }

        // scale + causal mask
#pragma unroll
        for (int qi = 0; qi < 2; ++qi)
#pragma unroll
            for (int j = 0; j < 4; ++j)
#pragma unroll
                for (int r = 0; r < 4; ++r) {
                    const int q  = q0 + wave * 32 + qi * 16 + quad * 4 + r;
                    const int kv = kv0 + j * 16 + l16;
                    const float s = sv[qi][j][r] * 0.125f;
                    sv[qi][j][r] = (kv <= q) ? s : -3.0e38f;
                }

        // online softmax (row stats across the 16 lanes of each quad-group)
#pragma unroll
        for (int qi = 0; qi < 2; ++qi) {
#pragma unroll
            for (int r = 0; r < 4; ++r) {
                float mx = fmaxf(fmaxf(sv[qi][0][r], sv[qi][1][r]),
                                 fmaxf(sv[qi][2][r], sv[qi][3][r]));
#pragma unroll
                for (int off = 1; off < 16; off <<= 1) mx = fmaxf(mx, __shfl_xor(mx, off, 16));
                const float newm  = fmaxf(mrow[qi][r], mx);
                const float alpha = __expf(mrow[qi][r] - newm);
                mrow[qi][r] = newm;
                float rsum = 0.f;
#pragma unroll
                for (int j = 0; j < 4; ++j) {
                    const float p = __expf(sv[qi][j][r] - newm);
                    sv[qi][j][r] = p;
                    rsum += p;
                }
#pragma unroll
                for (int off = 1; off < 16; off <<= 1) rsum += __shfl_xor(rsum, off, 16);
                lrow[qi][r] = lrow[qi][r] * alpha + rsum;
#pragma unroll
                for (int dj = 0; dj < 4; ++dj) Oacc[qi][dj][r] *= alpha;
            }
        }

        // P: C-layout regs -> LDS -> A-operand layout
#pragma unroll
        for (int qi = 0; qi < 2; ++qi)
#pragma unroll
            for (int j = 0; j < 4; ++j)
#pragma unroll
                for (int r = 0; r < 4; ++r)
                    Ps[wave][(qi * 16 + quad * 4 + r) * 72 + j * 16 + l16] = (bf16)sv[qi][j][r];
        __syncthreads();   // uniform across waves (loop count is block-level)

        bf16x8 pf[2][2], vf[4][2];
#pragma unroll
        for (int qi = 0; qi < 2; ++qi)
#pragma unroll
            for (int kk = 0; kk < 2; ++kk)
                pf[qi][kk] = *(const bf16x8*)&Ps[wave][(qi * 16 + l16) * 72 + kk * 32 + quad * 8];
#pragma unroll
        for (int dj = 0; dj < 4; ++dj)
#pragma unroll
            for (int kk = 0; kk < 2; ++kk)
                vf[dj][kk] = *(const bf16x8*)&Vt[(dj * 16 + l16) * 72 + kk * 32 + quad * 8];
#pragma unroll
        for (int qi = 0; qi < 2; ++qi)
#pragma unroll
            for (int dj = 0; dj < 4; ++dj) {
                Oacc[qi][dj] = __builtin_amdgcn_mfma_f32_16x16x32_bf16(pf[qi][0], vf[dj][0], Oacc[qi][dj], 0, 0, 0);
                Oacc[qi][dj] = __builtin_amdgcn_mfma_f32_16x16x32_bf16(pf[qi][1], vf[dj][1], Oacc[qi][dj], 0, 0, 0);
            }
    }

    // epilogue: O /= l, token-major write
#pragma unroll
    for (int qi = 0; qi < 2; ++qi)
#pragma unroll
        for (int dj = 0; dj < 4; ++dj)
#pragma unroll
            for (int r = 0; r < 4; ++r) {
                const int q = q0 + wave * 32 + qi * 16 + quad * 4 + r;
                const float o = Oacc[qi][dj][r] / lrow[qi][r];
                out[((size_t)(b * SEQ + q)) * D_MODEL + h * DK + dj * 16 + l16] = (bf16)o;
            }
}

// ---------------------------------------------------------------- launch
extern "C" void kernel_launch(void* const* d_in, const int* in_sizes, int n_in,
                              void* d_out, int out_size, void* d_ws, size_t ws_size,
                              hipStream_t stream)
{
    const float* x    = (const float*)d_in[0];
    const float* Wq   = (const float*)d_in[1];
    const float* bq   = (const float*)d_in[2];
    const float* Wk   = (const float*)d_in[3];
    const float* bk   = (const float*)d_in[4];
    const float* Wv   = (const float*)d_in[5];
    const float* bv   = (const float*)d_in[6];
    const float* Wo   = (const float*)d_in[7];
    const float* bo   = (const float*)d_in[8];
    const float* W1   = (const float*)d_in[9];
    const float* b1   = (const float*)d_in[10];
    const float* W2   = (const float*)d_in[11];
    const float* b2   = (const float*)d_in[12];
    const float* ln1g = (const float*)d_in[13];
    const float* ln1b = (const float*)d_in[14];
    const float* ln2g = (const float*)d_in[15];
    const float* ln2b = (const float*)d_in[16];

    char* ws = (char*)d_ws;
    const size_t MB = 1024 * 1024;
    bf16* WTq  = (bf16*)(ws + 0 * MB);   // [1024][1024]
    bf16* WTk  = (bf16*)(ws + 2 * MB);
    bf16* WTv  = (bf16*)(ws + 4 * MB);
    bf16* WTo  = (bf16*)(ws + 6 * MB);
    bf16* WT1  = (bf16*)(ws + 8 * MB);   // [4096][1024]
    bf16* WT2  = (bf16*)(ws + 16 * MB);  // [1024][4096]
    bf16* hbuf = (bf16*)(ws + 24 * MB);  // h1 then h2 (16 MB)
    bf16* Qh   = (bf16*)(ws + 40 * MB);  // [64][2048][64] (16 MB)
    bf16* Kh   = (bf16*)(ws + 56 * MB);
    bf16* Vh   = (bf16*)(ws + 72 * MB);
    bf16* attn = (bf16*)(ws + 88 * MB);  // [8192][1024]
    bf16* ff1  = (bf16*)(ws + 40 * MB);  // aliases Qh/Kh/Vh/attn region (free by then), 64 MB
    float* x2  = (float*)d_out;          // fp32 residual stream lives in d_out

    dim3 tb(32, 8);
    transpose_cast<<<dim3(32, 32),  tb, 0, stream>>>(Wq, WTq, 1024, 1024);
    transpose_cast<<<dim3(32, 32),  tb, 0, stream>>>(Wk, WTk, 1024, 1024);
    transpose_cast<<<dim3(32, 32),  tb, 0, stream>>>(Wv, WTv, 1024, 1024);
    transpose_cast<<<dim3(32, 32),  tb, 0, stream>>>(Wo, WTo, 1024, 1024);
    transpose_cast<<<dim3(128, 32), tb, 0, stream>>>(W1, WT1, 1024, 4096);
    transpose_cast<<<dim3(32, 128), tb, 0, stream>>>(W2, WT2, 4096, 1024);

    ln_kernel<<<NTOK, 256, 0, stream>>>(x, ln1g, ln1b, hbuf);

    gemm_bf16<0><<<dim3(8, 64), 256, 0, stream>>>(hbuf, WTq, bq, nullptr, Qh, NTOK, 1024, 1024);
    gemm_bf16<0><<<dim3(8, 64), 256, 0, stream>>>(hbuf, WTk, bk, nullptr, Kh, NTOK, 1024, 1024);
    gemm_bf16<0><<<dim3(8, 64), 256, 0, stream>>>(hbuf, WTv, bv, nullptr, Vh, NTOK, 1024, 1024);

    attn_kernel<<<dim3(16, 64), 256, 0, stream>>>(Qh, Kh, Vh, attn);

    gemm_bf16<1><<<dim3(8, 64), 256, 0, stream>>>(attn, WTo, bo, x, x2, NTOK, 1024, 1024);

    ln_kernel<<<NTOK, 256, 0, stream>>>(x2, ln2g, ln2b, hbuf);

    gemm_bf16<2><<<dim3(32, 64), 256, 0, stream>>>(hbuf, WT1, b1, nullptr, ff1, NTOK, 4096, 1024);
    gemm_bf16<1><<<dim3(8, 64),  256, 0, stream>>>(ff1, WT2, b2, x2, x2, NTOK, 1024, 4096);
}

// Round 2
// 571.929 us; speedup vs baseline: 1.3143x; 1.3143x over previous
//
#include <hip/hip_runtime.h>
#include <hip/hip_bf16.h>

typedef __bf16 bf16;
typedef __attribute__((ext_vector_type(8))) __bf16 bf16x8;
typedef __attribute__((ext_vector_type(4))) float f32x4;

#define D_MODEL 1024
#define NHEADS  16
#define DK      64
#define DFF     4096
#define BATCH   4
#define SEQ     2048
#define NTOK    (BATCH*SEQ)   // 8192

__device__ __forceinline__ void gload16(const bf16* g, bf16* l) {
    __builtin_amdgcn_global_load_lds((const __attribute__((address_space(1))) void*)g,
                                     (__attribute__((address_space(3))) void*)l, 16, 0, 0);
}

__device__ __forceinline__ int pack2(float a, float b) {
    union { bf16 h[2]; int i; } u;
    u.h[0] = (bf16)a; u.h[1] = (bf16)b;
    return u.i;
}

// ---------------------------------------------------------------- transpose+cast
// W[K][N] fp32 -> Wt[N][K] bf16
__global__ __launch_bounds__(256) void transpose_cast(
    const float* __restrict__ W, bf16* __restrict__ Wt, int K, int N)
{
    __shared__ float tile[32][33];
    const int tx = threadIdx.x, ty = threadIdx.y;
    const int n0 = blockIdx.x * 32, k0 = blockIdx.y * 32;
#pragma unroll
    for (int i = 0; i < 4; ++i)
        tile[ty + i*8][tx] = W[(size_t)(k0 + ty + i*8) * N + n0 + tx];
    __syncthreads();
#pragma unroll
    for (int i = 0; i < 4; ++i)
        Wt[(size_t)(n0 + ty + i*8) * K + k0 + tx] = (bf16)tile[tx][ty + i*8];
}

// ---------------------------------------------------------------- V head-transpose
// Vh[bh][s][64] -> VhT[bh][64][2048]
__global__ __launch_bounds__(256) void transpose_v(
    const bf16* __restrict__ V, bf16* __restrict__ VT)
{
    __shared__ bf16 t[64][72];
    const int bh = blockIdx.y;
    const int s0 = blockIdx.x * 64;
    const int r  = threadIdx.x >> 2;         // 0..63
    const int c0 = (threadIdx.x & 3) * 16;   // 0,16,32,48
    const bf16* Vb = V  + (size_t)bh * SEQ * DK;
    bf16*       Tb = VT + (size_t)bh * DK * SEQ;
#pragma unroll
    for (int i = 0; i < 2; ++i) {
        bf16x8 v = *(const bf16x8*)&Vb[(size_t)(s0 + r) * DK + c0 + i*8];
#pragma unroll
        for (int j = 0; j < 8; ++j) t[c0 + i*8 + j][r] = v[j];
    }
    __syncthreads();
#pragma unroll
    for (int i = 0; i < 2; ++i) {
        bf16x8 o;
#pragma unroll
        for (int j = 0; j < 8; ++j) o[j] = t[r][c0 + i*8 + j];
        *(bf16x8*)&Tb[(size_t)r * SEQ + s0 + c0 + i*8] = o;
    }
}

// ---------------------------------------------------------------- layernorm (fp32 in, bf16 out)
__global__ __launch_bounds__(256) void ln_kernel(
    const float* __restrict__ x, const float* __restrict__ g,
    const float* __restrict__ beta, bf16* __restrict__ out)
{
    const int row = blockIdx.x, tid = threadIdx.x;
    const f32x4* xr = (const f32x4*)(x + (size_t)row * D_MODEL);
    f32x4 v = xr[tid];
    float s  = v[0] + v[1] + v[2] + v[3];
    float s2 = v[0]*v[0] + v[1]*v[1] + v[2]*v[2] + v[3]*v[3];
#pragma unroll
    for (int off = 32; off > 0; off >>= 1) {
        s  += __shfl_down(s,  off, 64);
        s2 += __shfl_down(s2, off, 64);
    }
    __shared__ float red[8];
    const int wave = tid >> 6, lane = tid & 63;
    if (lane == 0) { red[wave] = s; red[wave + 4] = s2; }
    __syncthreads();
    if (tid == 0) {
        float a = red[0] + red[1] + red[2] + red[3];
        float c = red[4] + red[5] + red[6] + red[7];
        float mu  = a * (1.0f / D_MODEL);
        float var = c * (1.0f / D_MODEL) - mu * mu;
        red[0] = mu;
        red[1] = rsqrtf(var + 1e-5f);
    }
    __syncthreads();
    const float mu = red[0], rs = red[1];
    f32x4 gv = ((const f32x4*)g)[tid];
    f32x4 bv = ((const f32x4*)beta)[tid];
    union { bf16 h[4]; uint2 u; } o;
#pragma unroll
    for (int i = 0; i < 4; ++i) o.h[i] = (bf16)((v[i] - mu) * rs * gv[i] + bv[i]);
    *(uint2*)(out + (size_t)row * D_MODEL + tid * 4) = o.u;
}

// ---------------------------------------------------------------- bf16 GEMM, 128x128 tile, BK=32
// m97 structure: global_load_lds width=16 into swizzled unpadded LDS tile.
// A[M][K] bf16, Bt[N][K] bf16 (= B^T), C = A·B + bias (+epilogue)
// EPI 0: head-scatter bf16 out[bh][s][dk]   (QKV)
// EPI 1: fp32 out = acc + bias + resid      (O-proj, FFN2)
// EPI 2: bf16 out = relu(acc + bias)        (FFN1)
template<int EPI>
__global__ __launch_bounds__(256, 2) void gemm_bf16(
    const bf16* __restrict__ A, const bf16* __restrict__ Bt,
    const float* __restrict__ bias, const float* __restrict__ resid,
    void* __restrict__ outp, int M, int N, int K)
{
    __shared__ __align__(16) bf16 As[128 * 32];
    __shared__ __align__(16) bf16 Bs[128 * 32];
    const int tid  = threadIdx.x;
    const int wave = tid >> 6, lane = tid & 63;
    const int quad = lane >> 4, l16 = lane & 15;
    const int wr = wave >> 1, wc = wave & 1;
    const int m0 = blockIdx.y * 128, n0 = blockIdx.x * 128;

    // staging: wave w call c stages rows [32w+16c, +16); lane -> row 32w+16c+(lane>>2),
    // LDS unit c'=lane&3, global unit u = (c' - (row>>1)&3) & 3   (additive swizzle)
    const int r0 = wave * 32 + (lane >> 2);
    const int r1 = r0 + 16;
    const int u0 = ((lane & 3) - ((r0 >> 1) & 3)) & 3;
    const int u1 = ((lane & 3) - ((r1 >> 1) & 3)) & 3;
    const bf16* gA0 = A  + (size_t)(m0 + r0) * K + u0 * 8;
    const bf16* gA1 = A  + (size_t)(m0 + r1) * K + u1 * 8;
    const bf16* gB0 = Bt + (size_t)(n0 + r0) * K + u0 * 8;
    const bf16* gB1 = Bt + (size_t)(n0 + r1) * K + u1 * 8;
    bf16* lA0 = As + wave * 1024;
    bf16* lA1 = As + wave * 1024 + 512;
    bf16* lB0 = Bs + wave * 1024;
    bf16* lB1 = Bs + wave * 1024 + 512;

    int aoff[4], boff[4];
#pragma unroll
    for (int i = 0; i < 4; ++i) {
        const int ra = wr * 64 + i * 16 + l16;
        aoff[i] = ra * 32 + ((quad + ((ra >> 1) & 3)) & 3) * 8;
        const int rb = wc * 64 + i * 16 + l16;
        boff[i] = rb * 32 + ((quad + ((rb >> 1) & 3)) & 3) * 8;
    }

    const f32x4 vzero = {0.f, 0.f, 0.f, 0.f};
    f32x4 acc[4][4];
#pragma unroll
    for (int i = 0; i < 4; ++i)
#pragma unroll
        for (int j = 0; j < 4; ++j) acc[i][j] = vzero;

    for (int k0 = 0; k0 < K; k0 += 32) {
        __syncthreads();
        gload16(gA0 + k0, lA0);
        gload16(gA1 + k0, lA1);
        gload16(gB0 + k0, lB0);
        gload16(gB1 + k0, lB1);
        __syncthreads();
        bf16x8 af[4], bfr[4];
#pragma unroll
        for (int i = 0; i < 4; ++i) af[i]  = *(const bf16x8*)&As[aoff[i]];
#pragma unroll
        for (int j = 0; j < 4; ++j) bfr[j] = *(const bf16x8*)&Bs[boff[j]];
#pragma unroll
        for (int i = 0; i < 4; ++i)
#pragma unroll
            for (int j = 0; j < 4; ++j)
                acc[i][j] = __builtin_amdgcn_mfma_f32_16x16x32_bf16(af[i], bfr[j], acc[i][j], 0, 0, 0);
    }

#pragma unroll
    for (int i = 0; i < 4; ++i) {
#pragma unroll
        for (int j = 0; j < 4; ++j) {
            const int col = n0 + wc * 64 + j * 16 + l16;
            const float bcol = bias[col];
#pragma unroll
            for (int r = 0; r < 4; ++r) {
                const int row = m0 + wr * 64 + i * 16 + quad * 4 + r;
                const float v = acc[i][j][r] + bcol;
                if (EPI == 0) {
                    const int bb = row >> 11, ss = row & (SEQ - 1);
                    const int hh = col >> 6,  dd = col & (DK - 1);
                    ((bf16*)outp)[((size_t)(bb * NHEADS + hh) * SEQ + ss) * DK + dd] = (bf16)v;
                } else if (EPI == 1) {
                    const size_t idx = (size_t)row * N + col;
                    ((float*)outp)[idx] = v + resid[idx];
                } else {
                    ((bf16*)outp)[(size_t)row * N + col] = (bf16)fmaxf(v, 0.f);
                }
            }
        }
    }
}

// ---------------------------------------------------------------- flash attention (causal), S^T layout
// Q/K: [B*H][S][64] bf16; VT: [B*H][64][S] bf16; out: [B][S][H*64] bf16.
// Block = 4 waves = 128 q rows. Grid (8, BH): block does qt = 15-bx, then bx (balanced: 17 kv-iters).
// S^T = K·Q^T: lane owns q-column l16; softmax = 2 shuffles; P^T stays in regs,
// PV B-operand built with 8 shfl + selects (no LDS round-trip).
__global__ __launch_bounds__(256, 2) void attn_kernel(
    const bf16* __restrict__ Q, const bf16* __restrict__ K,
    const bf16* __restrict__ VT, bf16* __restrict__ out)
{
    const int bh = blockIdx.y;
    const int b = bh >> 4, h = bh & 15;
    const int tid  = threadIdx.x;
    const int wave = tid >> 6, lane = tid & 63;
    const int quad = lane >> 4, l16 = lane & 15;

    __shared__ __align__(16) bf16 Ks[128 * 72];   // [kv][d] pad 72
    __shared__ __align__(16) bf16 Vt[64 * 136];   // [d][kv] pad 136

    const bf16* Qb = Q  + (size_t)bh * SEQ * DK;
    const bf16* Kb = K  + (size_t)bh * SEQ * DK;
    const bf16* Vb = VT + (size_t)bh * DK * SEQ;

    const int srcA = (2 * (quad & 1)) * 16 + l16;  // shfl source lanes for PV frag
    const int srcB = srcA + 16;
    const bool thi = quad >= 2;

    const f32x4 vzero = {0.f, 0.f, 0.f, 0.f};

    for (int half = 0; half < 2; ++half) {
        const int qt = half ? (int)blockIdx.x : 15 - (int)blockIdx.x;
        const int qw = qt * 128 + wave * 32;

        // Q fragments (B-operand: n=q=l16, k=d=quad*8+i)
        bf16x8 qf[2][2];
#pragma unroll
        for (int qi = 0; qi < 2; ++qi)
#pragma unroll
            for (int kk = 0; kk < 2; ++kk)
                qf[qi][kk] = *(const bf16x8*)&Qb[(size_t)(qw + qi*16 + l16) * DK + kk*32 + quad*8];

        f32x4 Oacc[2][4];
        float m_[2], l_[2];
#pragma unroll
        for (int qi = 0; qi < 2; ++qi) {
            m_[qi] = -3.0e38f; l_[qi] = 0.f;
#pragma unroll
            for (int dj = 0; dj < 4; ++dj) Oacc[qi][dj] = vzero;
        }

        const int ntiles = qt + 1;
        for (int t = 0; t < ntiles; ++t) {
            const int kv0 = t * 128;
            __syncthreads();
            // stage K tile [128 kv][64 d]
            for (int c = tid; c < 1024; c += 256) {
                const int r = c >> 3, u = c & 7;
                *(f32x4*)&Ks[r * 72 + u * 8] = *(const f32x4*)&Kb[(size_t)(kv0 + r) * DK + u * 8];
            }
            // stage V^T tile [64 d][128 kv]
            for (int c = tid; c < 1024; c += 256) {
                const int r = c >> 4, u = c & 15;
                *(f32x4*)&Vt[r * 136 + u * 8] = *(const f32x4*)&Vb[(size_t)r * SEQ + kv0 + u * 8];
            }
            __syncthreads();

            // S^T = K·Q^T : C-layout rows = kv, cols = q
            f32x4 sv[8][2];
#pragma unroll
            for (int kvt = 0; kvt < 8; ++kvt) {
                bf16x8 kf0 = *(const bf16x8*)&Ks[(kvt*16 + l16) * 72 + quad*8];
                bf16x8 kf1 = *(const bf16x8*)&Ks[(kvt*16 + l16) * 72 + 32 + quad*8];
#pragma unroll
                for (int qi = 0; qi < 2; ++qi) {
                    f32x4 tacc = vzero;
                    tacc = __builtin_amdgcn_mfma_f32_16x16x32_bf16(kf0, qf[qi][0], tacc, 0, 0, 0);
                    tacc = __builtin_amdgcn_mfma_f32_16x16x32_bf16(kf1, qf[qi][1], tacc, 0, 0, 0);
                    sv[kvt][qi] = tacc;
                }
            }

            const float scale = 0.125f;
            if (t == qt) {   // diagonal tile: mask
#pragma unroll
                for (int kvt = 0; kvt < 8; ++kvt)
#pragma unroll
                    for (int qi = 0; qi < 2; ++qi)
#pragma unroll
                        for (int r = 0; r < 4; ++r) {
                            const int kv = kv0 + kvt*16 + quad*4 + r;
                            const int q  = qw + qi*16 + l16;
                            sv[kvt][qi][r] = (kv <= q) ? sv[kvt][qi][r] * scale : -3.0e38f;
                        }
            } else {
#pragma unroll
                for (int kvt = 0; kvt < 8; ++kvt)
#pragma unroll
                    for (int qi = 0; qi < 2; ++qi)
#pragma unroll
                        for (int r = 0; r < 4; ++r) sv[kvt][qi][r] *= scale;
            }

            // online softmax per q-column (lane-resident; cross-quad = 2 shuffles)
#pragma unroll
            for (int qi = 0; qi < 2; ++qi) {
                float mx = sv[0][qi][0];
#pragma unroll
                for (int kvt = 0; kvt < 8; ++kvt)
#pragma unroll
                    for (int r = 0; r < 4; ++r) mx = fmaxf(mx, sv[kvt][qi][r]);
                mx = fmaxf(mx, __shfl_xor(mx, 16, 64));
                mx = fmaxf(mx, __shfl_xor(mx, 32, 64));
                const float newm  = fmaxf(m_[qi], mx);
                const float alpha = __expf(m_[qi] - newm);
                m_[qi] = newm;
                float rs = 0.f;
#pragma unroll
                for (int kvt = 0; kvt < 8; ++kvt)
#pragma unroll
                    for (int r = 0; r < 4; ++r) {
                        const float p = __expf(sv[kvt][qi][r] - newm);
                        sv[kvt][qi][r] = p;
                        rs += p;
                    }
                rs += __shfl_xor(rs, 16, 64);
                rs += __shfl_xor(rs, 32, 64);
                l_[qi] = l_[qi] * alpha + rs;
#pragma unroll
                for (int dj = 0; dj < 4; ++dj) Oacc[qi][dj] *= alpha;
            }

            // O^T += V^T · P^T  (32-kv chunks; P B-operand via shfl re-layout)
#pragma unroll
            for (int c2 = 0; c2 < 4; ++c2) {
                bf16x8 vf[4];
#pragma unroll
                for (int dj = 0; dj < 4; ++dj)
                    vf[dj] = *(const bf16x8*)&Vt[(dj*16 + l16) * 136 + c2*32 + quad*8];
#pragma unroll
                for (int qi = 0; qi < 2; ++qi) {
                    const int p00 = pack2(sv[2*c2][qi][0],   sv[2*c2][qi][1]);
                    const int p01 = pack2(sv[2*c2][qi][2],   sv[2*c2][qi][3]);
                    const int p10 = pack2(sv[2*c2+1][qi][0], sv[2*c2+1][qi][1]);
                    const int p11 = pack2(sv[2*c2+1][qi][2], sv[2*c2+1][qi][3]);
                    const int a0 = __shfl(p00, srcA, 64), a1 = __shfl(p01, srcA, 64);
                    const int a2 = __shfl(p10, srcA, 64), a3 = __shfl(p11, srcA, 64);
                    const int b0 = __shfl(p00, srcB, 64), b1 = __shfl(p01, srcB, 64);
                    const int b2 = __shfl(p10, srcB, 64), b3 = __shfl(p11, srcB, 64);
                    union { int i[4]; bf16x8 v; } pf;
                    pf.i[0] = thi ? a2 : a0;
                    pf.i[1] = thi ? a3 : a1;
                    pf.i[2] = thi ? b2 : b0;
                    pf.i[3] = thi ? b3 : b1;
#pragma unroll
                    for (int dj = 0; dj < 4; ++dj)
                        Oacc[qi][dj] = __builtin_amdgcn_mfma_f32_16x16x32_bf16(vf[dj], pf.v, Oacc[qi][dj], 0, 0, 0);
                }
            }
        }

        // epilogue: O^T C-layout -> token-major out
#pragma unroll
        for (int qi = 0; qi < 2; ++qi) {
            const float inv = 1.0f / l_[qi];
            const int q = qw + qi*16 + l16;
#pragma unroll
            for (int dj = 0; dj < 4; ++dj)
#pragma unroll
                for (int r = 0; r < 4; ++r) {
                    const int d = dj*16 + quad*4 + r;
                    out[((size_t)(b * SEQ + q)) * D_MODEL + h * DK + d] = (bf16)(Oacc[qi][dj][r] * inv);
                }
        }
    }
}

// ---------------------------------------------------------------- launch
extern "C" void kernel_launch(void* const* d_in, const int* in_sizes, int n_in,
                              void* d_out, int out_size, void* d_ws, size_t ws_size,
                              hipStream_t stream)
{
    const float* x    = (const float*)d_in[0];
    const float* Wq   = (const float*)d_in[1];
    const float* bq   = (const float*)d_in[2];
    const float* Wk   = (const float*)d_in[3];
    const float* bk   = (const float*)d_in[4];
    const float* Wv   = (const float*)d_in[5];
    const float* bv   = (const float*)d_in[6];
    const float* Wo   = (const float*)d_in[7];
    const float* bo   = (const float*)d_in[8];
    const float* W1   = (const float*)d_in[9];
    const float* b1   = (const float*)d_in[10];
    const float* W2   = (const float*)d_in[11];
    const float* b2   = (const float*)d_in[12];
    const float* ln1g = (const float*)d_in[13];
    const float* ln1b = (const float*)d_in[14];
    const float* ln2g = (const float*)d_in[15];
    const float* ln2b = (const float*)d_in[16];

    char* ws = (char*)d_ws;
    const size_t MB = 1024 * 1024;
    bf16* WTq  = (bf16*)(ws + 0 * MB);   // [1024][1024]
    bf16* WTk  = (bf16*)(ws + 2 * MB);
    bf16* WTv  = (bf16*)(ws + 4 * MB);
    bf16* WTo  = (bf16*)(ws + 6 * MB);
    bf16* WT1  = (bf16*)(ws + 8 * MB);   // [4096][1024]
    bf16* WT2  = (bf16*)(ws + 16 * MB);  // [1024][4096]
    bf16* hbuf = (bf16*)(ws + 24 * MB);  // h1; later h2 (16 MB)
    bf16* VhT  = (bf16*)(ws + 24 * MB);  // aliases hbuf: h1 dead after QKV GEMMs, VhT dead before LN2
    bf16* Qh   = (bf16*)(ws + 40 * MB);  // [64][2048][64]
    bf16* Kh   = (bf16*)(ws + 56 * MB);
    bf16* Vh   = (bf16*)(ws + 72 * MB);
    bf16* attn = (bf16*)(ws + 88 * MB);  // [8192][1024]
    bf16* ff1  = (bf16*)(ws + 40 * MB);  // aliases Qh/Kh/Vh/attn (free after O-proj)
    float* x2  = (float*)d_out;          // fp32 residual stream in d_out

    dim3 tb(32, 8);
    transpose_cast<<<dim3(32, 32),  tb, 0, stream>>>(Wq, WTq, 1024, 1024);
    transpose_cast<<<dim3(32, 32),  tb, 0, stream>>>(Wk, WTk, 1024, 1024);
    transpose_cast<<<dim3(32, 32),  tb, 0, stream>>>(Wv, WTv, 1024, 1024);
    transpose_cast<<<dim3(32, 32),  tb, 0, stream>>>(Wo, WTo, 1024, 1024);
    transpose_cast<<<dim3(128, 32), tb, 0, stream>>>(W1, WT1, 1024, 4096);
    transpose_cast<<<dim3(32, 128), tb, 0, stream>>>(W2, WT2, 4096, 1024);

    ln_kernel<<<NTOK, 256, 0, stream>>>(x, ln1g, ln1b, hbuf);

    gemm_bf16<0><<<dim3(8, 64), 256, 0, stream>>>(hbuf, WTq, bq, nullptr, Qh, NTOK, 1024, 1024);
    gemm_bf16<0><<<dim3(8, 64), 256, 0, stream>>>(hbuf, WTk, bk, nullptr, Kh, NTOK, 1024, 1024);
    gemm_bf16<0><<<dim3(8, 64), 256, 0, stream>>>(hbuf, WTv, bv, nullptr, Vh, NTOK, 1024, 1024);

    transpose_v<<<dim3(32, 64), 256, 0, stream>>>(Vh, VhT);   // h1 consumed; reuse its slot

    attn_kernel<<<dim3(8, 64), 256, 0, stream>>>(Qh, Kh, VhT, attn);

    gemm_bf16<1><<<dim3(8, 64), 256, 0, stream>>>(attn, WTo, bo, x, x2, NTOK, 1024, 1024);

    ln_kernel<<<NTOK, 256, 0, stream>>>(x2, ln2g, ln2b, hbuf);

    gemm_bf16<2><<<dim3(32, 64), 256, 0, stream>>>(hbuf, WT1, b1, nullptr, ff1, NTOK, 4096, 1024);
    gemm_bf16<1><<<dim3(8, 64),  256, 0, stream>>>(ff1, WT2, b2, x2, x2, NTOK, 1024, 4096);
}